// Round 1
// baseline (873.640 us; speedup 1.0000x reference)
//
#include <hip/hip_runtime.h>
#include <cmath>

// ---------------------------------------------------------------------------
// PCSM loss, fused:
//   kernel 1: per-pixel OD/fod + 32x32 Gram partials + fod_relu row sums
//   kernel 2: cosine-normalize, L1 mean + avg-MSE term -> scalar
// ---------------------------------------------------------------------------

#define HW   262144          // 512*512
#define CHW  (3*HW)
#define NIMG 32
#define CPB  512             // pixel columns per block
#define GRIDX (HW / CPB)     // 512 blocks per tensor

// RGB_FROM_HED and its inverse column 2 (DAB), computed exactly in double.
constexpr double M00=0.65, M01=0.70, M02=0.29;
constexpr double M10=0.07, M11=0.99, M12=0.11;
constexpr double M20=0.27, M21=0.57, M22=0.78;
constexpr double DETM = M00*(M11*M22-M12*M21) - M01*(M10*M22-M12*M20)
                      + M02*(M10*M21-M11*M20);
constexpr double H0d =  (M01*M12 - M02*M11) / DETM;   // hed_from_rgb[0][2]
constexpr double H1d = -(M00*M12 - M02*M10) / DETM;   // hed_from_rgb[1][2]
constexpr double H2d =  (M00*M11 - M01*M10) / DETM;   // hed_from_rgb[2][2]

#define H0 ((float)H0d)
#define H1 ((float)H1d)
#define H2 ((float)H2d)

// fod for one pixel. All transcendentals in base-2 HW ops.
// t2 = log2-space equivalent of LOG_ADJUST*d (ln2/log2e cancel):
//   d = max((h . ln(rgb))/ln(1e-6), 0)  ==>  LOG_ADJUST*d*log2e = min(h . log2(rgb), 0)
__device__ __forceinline__ float fod1(float r, float g, float b, float cal,
                                      float& racc) {
  float lr = __log2f(fmaxf(r, 1e-6f));
  float lg = __log2f(fmaxf(g, 1e-6f));
  float lb = __log2f(fmaxf(b, 1e-6f));
  float t2 = fminf(lr*H0 + lg*H1 + lb*H2, 0.0f);
  float e0 = exp2f(t2 * 0.27f);              // rgb_from_hed[2] weights
  float e1 = exp2f(t2 * 0.57f);
  float e2 = exp2f(t2 * 0.78f);
  float grey = fminf(e0*0.2125f + e1*0.7154f + e2*0.0721f, 1.0f);
  float x = fmaxf(-0.30102999566398120f * __log2f(grey + cal), 0.0f);
  float f = exp2f(1.8f * __log2f(x));        // x^1.8 ; x==0 -> exp2(-inf)=0
  racc += (f < 0.15f) ? 0.0f : f;            // THRESH_FOD
  return f;
}

// ws layout (floats): [0..1023] gram tgt, [1024..2047] gram gen,
//                     [2048..2079] avg tgt, [2080..2111] avg gen
__global__ __launch_bounds__(256, 4)
void od_gram_kernel(const float* __restrict__ tgt, const float* __restrict__ gen,
                    float* __restrict__ ws, float cal) {
  const float* img  = blockIdx.y ? gen : tgt;
  float* gram = ws + (blockIdx.y << 10);
  float* avgv = ws + 2048 + (blockIdx.y << 5);

  // F[b][k'] : 32 rows x 256 pixels, XOR-swizzled at float4-group granularity
  // (group g stored at g ^ ((b>>2)&7)) -> conflict-free writes & row reads.
  __shared__ float F[NIMG * 256];

  const int t  = threadIdx.x;
  const int wv = t >> 6;        // wave id: phase A image-group, phase B k-quarter
  const int ln = t & 63;

  float acc[4][4];
  #pragma unroll
  for (int r = 0; r < 4; ++r)
    #pragma unroll
    for (int c = 0; c < 4; ++c) acc[r][c] = 0.0f;
  float avgp[8];
  #pragma unroll
  for (int r = 0; r < 8; ++r) avgp[r] = 0.0f;

  const int i0  = (ln >> 3) << 2;   // phase B 4x4 pair tile
  const int j0  = (ln & 7) << 2;
  const int swi = ln >> 3;          // = (i0>>2)&7
  const int swj = ln & 7;           // = (j0>>2)&7

  const int col0 = blockIdx.x * CPB;

  for (int tile = 0; tile < CPB / 256; ++tile) {
    const int k0 = col0 + (tile << 8);

    // ---- Phase A: wave wv computes images [8wv, 8wv+8), lane ln pixels 4ln..4ln+3
    #pragma unroll
    for (int r = 0; r < 8; ++r) {
      const int b = (wv << 3) + r;
      const float* base = img + b * CHW + k0 + (ln << 2);
      float4 Rv = *(const float4*)(base);
      float4 Gv = *(const float4*)(base + HW);
      float4 Bv = *(const float4*)(base + 2 * HW);
      float4 fo;
      fo.x = fod1(Rv.x, Gv.x, Bv.x, cal, avgp[r]);
      fo.y = fod1(Rv.y, Gv.y, Bv.y, cal, avgp[r]);
      fo.z = fod1(Rv.z, Gv.z, Bv.z, cal, avgp[r]);
      fo.w = fod1(Rv.w, Gv.w, Bv.w, cal, avgp[r]);
      const int sw = (b >> 2) & 7;
      *(float4*)&F[(b << 8) + ((ln ^ sw) << 2)] = fo;
    }
    __syncthreads();

    // ---- Phase B: Gram accumulate; wave wv owns k-quarter, thread a 4x4 pair tile
    #pragma unroll
    for (int gg = 0; gg < 16; ++gg) {
      const int gq = (wv << 4) + gg;   // pixel group (of 4) within tile
      float4 av[4], bv[4];
      #pragma unroll
      for (int r = 0; r < 4; ++r)
        av[r] = *(const float4*)&F[((i0 + r) << 8) + ((gq ^ swi) << 2)];
      #pragma unroll
      for (int c = 0; c < 4; ++c)
        bv[c] = *(const float4*)&F[((j0 + c) << 8) + ((gq ^ swj) << 2)];
      #pragma unroll
      for (int r = 0; r < 4; ++r)
        #pragma unroll
        for (int c = 0; c < 4; ++c)
          acc[r][c] += av[r].x * bv[c].x + av[r].y * bv[c].y +
                       av[r].z * bv[c].z + av[r].w * bv[c].w;
    }
    __syncthreads();
  }

  // ---- fod_relu row sums: shuffle-reduce within wave, one atomic per row
  #pragma unroll
  for (int r = 0; r < 8; ++r) {
    float v = avgp[r];
    #pragma unroll
    for (int off = 32; off; off >>= 1) v += __shfl_down(v, off, 64);
    if (ln == 0) atomicAdd(&avgv[(wv << 3) + r], v);
  }

  // ---- Gram: cross-wave (k-quarter) reduce in LDS, then atomics
  {
    const int base = t << 4;
    #pragma unroll
    for (int r = 0; r < 4; ++r)
      #pragma unroll
      for (int c = 0; c < 4; ++c)
        F[base + (r << 2) + c] = acc[r][c];
    __syncthreads();
    for (int e = t; e < 1024; e += 256) {
      const int i = e >> 5, j = e & 31;
      const int tij = ((i >> 2) << 3) + (j >> 2);
      const int idx = ((i & 3) << 2) + (j & 3);
      float sm = 0.0f;
      #pragma unroll
      for (int w2 = 0; w2 < 4; ++w2)
        sm += F[(((w2 << 6) + tij) << 4) + idx];
      atomicAdd(&gram[e], sm);
    }
  }
}

__global__ __launch_bounds__(256)
void finalize_kernel(const float* __restrict__ ws, float* __restrict__ out) {
  __shared__ float nrm[64];
  __shared__ float wred[8];
  const int t = threadIdx.x;
  if (t < 64) {
    const int tensor = t >> 5, i = t & 31;
    nrm[t] = fmaxf(sqrtf(ws[(tensor << 10) + i * 33]), 1e-8f);  // COS_EPS
  }
  __syncthreads();

  float s1 = 0.0f;
  for (int e = t; e < 1024; e += 256) {
    const int i = e >> 5, j = e & 31;
    const float ct = ws[e]        / (nrm[i]      * nrm[j]);
    const float cg = ws[1024 + e] / (nrm[32 + i] * nrm[32 + j]);
    s1 += fabsf(ct - cg);
  }
  float s2 = 0.0f;
  if (t < 32) {
    const float d = ws[2048 + t] - ws[2080 + t];
    s2 = d * d;
  }
  #pragma unroll
  for (int off = 32; off; off >>= 1) {
    s1 += __shfl_down(s1, off, 64);
    s2 += __shfl_down(s2, off, 64);
  }
  if ((t & 63) == 0) { wred[t >> 6] = s1; wred[4 + (t >> 6)] = s2; }
  __syncthreads();
  if (t == 0) {
    const float a = wred[0] + wred[1] + wred[2] + wred[3];
    const float b = wred[4] + wred[5] + wred[6] + wred[7];
    const double hw2 = 262144.0 * 262144.0;
    out[0] = (float)((double)a / 1024.0 + ((double)b / 32.0) / hw2);
  }
}

extern "C" void kernel_launch(void* const* d_in, const int* in_sizes, int n_in,
                              void* d_out, int out_size, void* d_ws, size_t ws_size,
                              hipStream_t stream) {
  (void)in_sizes; (void)n_in; (void)out_size; (void)ws_size;
  const float* tgt = (const float*)d_in[1];
  const float* gen = (const float*)d_in[2];
  float* out = (float*)d_out;
  float* ws  = (float*)d_ws;

  hipMemsetAsync(d_ws, 0, 2112 * sizeof(float), stream);

  const float cal = (float)pow(10.0, -exp(1.0 / 1.8));  // ADJUST_CAL

  dim3 grid(GRIDX, 2);
  od_gram_kernel<<<grid, 256, 0, stream>>>(tgt, gen, ws, cal);
  finalize_kernel<<<1, 256, 0, stream>>>(ws, out);
}

// Round 2
// 322.296 us; speedup vs baseline: 2.7107x; 2.7107x over previous
//
#include <hip/hip_runtime.h>
#include <cmath>

// ---------------------------------------------------------------------------
// PCSM loss, fused:
//   kernel 1: per-pixel OD/fod + 32x32 Gram partials (8-way replicated atomics)
//   kernel 2: sum replicas, cosine-normalize, L1 mean + avg-MSE term -> scalar
// Round-1 changes vs round-0:
//   * register-pressure control: #pragma unroll 2 on phase-A image loop,
//     streamed bv in phase B  -> peak ~75 VGPR, no spill at the 128 cap
//   * 8-way replicated gram/avg accumulators -> 8x less atomic contention
// ---------------------------------------------------------------------------

#define HW    262144          // 512*512
#define CHW   (3*HW)
#define NIMG  32
#define CPB   512             // pixel columns per block
#define GRIDX (HW / CPB)      // 512 blocks per tensor
#define NREP  8               // accumulator replicas

// RGB_FROM_HED and its inverse column 2 (DAB), computed exactly in double.
constexpr double M00=0.65, M01=0.70, M02=0.29;
constexpr double M10=0.07, M11=0.99, M12=0.11;
constexpr double M20=0.27, M21=0.57, M22=0.78;
constexpr double DETM = M00*(M11*M22-M12*M21) - M01*(M10*M22-M12*M20)
                      + M02*(M10*M21-M11*M20);
constexpr double H0d =  (M01*M12 - M02*M11) / DETM;   // hed_from_rgb[0][2]
constexpr double H1d = -(M00*M12 - M02*M10) / DETM;   // hed_from_rgb[1][2]
constexpr double H2d =  (M00*M11 - M01*M10) / DETM;   // hed_from_rgb[2][2]

#define H0 ((float)H0d)
#define H1 ((float)H1d)
#define H2 ((float)H2d)

// fod for one pixel. All transcendentals in base-2 HW ops.
//   d = max((h . ln(rgb))/ln(1e-6), 0)  ==>  LOG_ADJUST*d*log2e = min(h . log2(rgb), 0)
__device__ __forceinline__ float fod1(float r, float g, float b, float cal,
                                      float& racc) {
  float lr = __log2f(fmaxf(r, 1e-6f));
  float lg = __log2f(fmaxf(g, 1e-6f));
  float lb = __log2f(fmaxf(b, 1e-6f));
  float t2 = fminf(lr*H0 + lg*H1 + lb*H2, 0.0f);
  float e0 = exp2f(t2 * 0.27f);              // rgb_from_hed[2] weights
  float e1 = exp2f(t2 * 0.57f);
  float e2 = exp2f(t2 * 0.78f);
  float grey = fminf(e0*0.2125f + e1*0.7154f + e2*0.0721f, 1.0f);
  float x = fmaxf(-0.30102999566398120f * __log2f(grey + cal), 0.0f);
  float f = exp2f(1.8f * __log2f(x));        // x^1.8 ; x==0 -> exp2(-inf)=0
  racc += (f < 0.15f) ? 0.0f : f;            // THRESH_FOD
  return f;
}

// ws layout (floats):
//   gram: rep*2048 + tensor*1024 + e          [0, 16384)
//   avg : 16384 + rep*64 + tensor*32 + i      [16384, 16896)
__global__ __launch_bounds__(256, 4)
void od_gram_kernel(const float* __restrict__ tgt, const float* __restrict__ gen,
                    float* __restrict__ ws, float cal) {
  const float* img = blockIdx.y ? gen : tgt;
  const int rep = blockIdx.x & (NREP - 1);
  float* gram = ws + (rep << 11) + (blockIdx.y << 10);
  float* avgv = ws + 16384 + (rep << 6) + (blockIdx.y << 5);

  // F[b][k'] : 32 rows x 256 pixels, XOR-swizzled at float4-group granularity
  // (group g stored at g ^ ((b>>2)&7)) -> conflict-free writes & row reads.
  __shared__ float F[NIMG * 256];

  const int t  = threadIdx.x;
  const int wv = t >> 6;        // wave id: phase A image-group, phase B k-quarter
  const int ln = t & 63;

  float acc[4][4];
  #pragma unroll
  for (int r = 0; r < 4; ++r)
    #pragma unroll
    for (int c = 0; c < 4; ++c) acc[r][c] = 0.0f;
  float avgp[8];
  #pragma unroll
  for (int r = 0; r < 8; ++r) avgp[r] = 0.0f;

  const int i0  = (ln >> 3) << 2;   // phase B 4x4 pair tile
  const int j0  = (ln & 7) << 2;
  const int swi = ln >> 3;          // = (i0>>2)&7
  const int swj = ln & 7;           // = (j0>>2)&7

  const int col0 = blockIdx.x * CPB;

  for (int tile = 0; tile < CPB / 256; ++tile) {
    const int k0 = col0 + (tile << 8);

    // ---- Phase A: wave wv computes images [8wv, 8wv+8), lane ln pixels 4ln..4ln+3
    // unroll 2: cap in-flight global loads (register-pressure control)
    #pragma unroll 2
    for (int r = 0; r < 8; ++r) {
      const int b = (wv << 3) + r;
      const float* base = img + b * CHW + k0 + (ln << 2);
      float4 Rv = *(const float4*)(base);
      float4 Gv = *(const float4*)(base + HW);
      float4 Bv = *(const float4*)(base + 2 * HW);
      float4 fo;
      fo.x = fod1(Rv.x, Gv.x, Bv.x, cal, avgp[r]);
      fo.y = fod1(Rv.y, Gv.y, Bv.y, cal, avgp[r]);
      fo.z = fod1(Rv.z, Gv.z, Bv.z, cal, avgp[r]);
      fo.w = fod1(Rv.w, Gv.w, Bv.w, cal, avgp[r]);
      const int sw = (b >> 2) & 7;
      *(float4*)&F[(b << 8) + ((ln ^ sw) << 2)] = fo;
    }
    __syncthreads();

    // ---- Phase B: Gram accumulate; wave wv owns k-quarter, thread a 4x4 tile.
    // av[4] held, bv streamed one float4 at a time (register-pressure control).
    #pragma unroll 2
    for (int gg = 0; gg < 16; ++gg) {
      const int gq = (wv << 4) + gg;   // pixel group (of 4) within tile
      float4 av[4];
      #pragma unroll
      for (int r = 0; r < 4; ++r)
        av[r] = *(const float4*)&F[((i0 + r) << 8) + ((gq ^ swi) << 2)];
      #pragma unroll
      for (int c = 0; c < 4; ++c) {
        float4 bv = *(const float4*)&F[((j0 + c) << 8) + ((gq ^ swj) << 2)];
        #pragma unroll
        for (int r = 0; r < 4; ++r)
          acc[r][c] += av[r].x * bv.x + av[r].y * bv.y +
                       av[r].z * bv.z + av[r].w * bv.w;
      }
    }
    __syncthreads();
  }

  // ---- fod_relu row sums: shuffle-reduce within wave, one atomic per row
  #pragma unroll
  for (int r = 0; r < 8; ++r) {
    float v = avgp[r];
    #pragma unroll
    for (int off = 32; off; off >>= 1) v += __shfl_down(v, off, 64);
    if (ln == 0) atomicAdd(&avgv[(wv << 3) + r], v);
  }

  // ---- Gram: cross-wave (k-quarter) reduce in LDS, then replica atomics
  {
    const int base = t << 4;
    #pragma unroll
    for (int r = 0; r < 4; ++r)
      #pragma unroll
      for (int c = 0; c < 4; ++c)
        F[base + (r << 2) + c] = acc[r][c];
    __syncthreads();
    for (int e = t; e < 1024; e += 256) {
      const int i = e >> 5, j = e & 31;
      const int tij = ((i >> 2) << 3) + (j >> 2);
      const int idx = ((i & 3) << 2) + (j & 3);
      float sm = 0.0f;
      #pragma unroll
      for (int w2 = 0; w2 < 4; ++w2)
        sm += F[(((w2 << 6) + tij) << 4) + idx];
      atomicAdd(&gram[e], sm);
    }
  }
}

__global__ __launch_bounds__(256)
void finalize_kernel(const float* __restrict__ ws, float* __restrict__ out) {
  __shared__ float G[2048];
  __shared__ float A[64];
  __shared__ float nrm[64];
  __shared__ float wred[8];
  const int t = threadIdx.x;

  for (int e = t; e < 2048; e += 256) {
    float s = 0.0f;
    #pragma unroll
    for (int r = 0; r < NREP; ++r) s += ws[(r << 11) + e];
    G[e] = s;
  }
  if (t < 64) {
    float s = 0.0f;
    #pragma unroll
    for (int r = 0; r < NREP; ++r) s += ws[16384 + (r << 6) + t];
    A[t] = s;
  }
  __syncthreads();

  if (t < 64) {
    const int tensor = t >> 5, i = t & 31;
    nrm[t] = fmaxf(sqrtf(G[(tensor << 10) + i * 33]), 1e-8f);  // COS_EPS
  }
  __syncthreads();

  float s1 = 0.0f;
  for (int e = t; e < 1024; e += 256) {
    const int i = e >> 5, j = e & 31;
    const float ct = G[e]        / (nrm[i]      * nrm[j]);
    const float cg = G[1024 + e] / (nrm[32 + i] * nrm[32 + j]);
    s1 += fabsf(ct - cg);
  }
  float s2 = 0.0f;
  if (t < 32) {
    const float d = A[t] - A[32 + t];
    s2 = d * d;
  }
  #pragma unroll
  for (int off = 32; off; off >>= 1) {
    s1 += __shfl_down(s1, off, 64);
    s2 += __shfl_down(s2, off, 64);
  }
  if ((t & 63) == 0) { wred[t >> 6] = s1; wred[4 + (t >> 6)] = s2; }
  __syncthreads();
  if (t == 0) {
    const float a = wred[0] + wred[1] + wred[2] + wred[3];
    const float b = wred[4] + wred[5] + wred[6] + wred[7];
    const double hw2 = 262144.0 * 262144.0;
    out[0] = (float)((double)a / 1024.0 + ((double)b / 32.0) / hw2);
  }
}

extern "C" void kernel_launch(void* const* d_in, const int* in_sizes, int n_in,
                              void* d_out, int out_size, void* d_ws, size_t ws_size,
                              hipStream_t stream) {
  (void)in_sizes; (void)n_in; (void)out_size; (void)ws_size;
  const float* tgt = (const float*)d_in[1];
  const float* gen = (const float*)d_in[2];
  float* out = (float*)d_out;
  float* ws  = (float*)d_ws;

  hipMemsetAsync(d_ws, 0, 16896 * sizeof(float), stream);

  const float cal = (float)pow(10.0, -exp(1.0 / 1.8));  // ADJUST_CAL

  dim3 grid(GRIDX, 2);
  od_gram_kernel<<<grid, 256, 0, stream>>>(tgt, gen, ws, cal);
  finalize_kernel<<<1, 256, 0, stream>>>(ws, out);
}

// Round 3
// 318.907 us; speedup vs baseline: 2.7395x; 1.0106x over previous
//
#include <hip/hip_runtime.h>
#include <cmath>

// ---------------------------------------------------------------------------
// PCSM loss, fused, MFMA Gram:
//   kernel 1: per-pixel OD/fod (f32) -> bf16 LDS tile -> G += mfma(a, a, acc)
//             (A-frag == B-frag for F*F^T; k-permutation cancels since a==b)
//   kernel 2: sum replicas, cosine-normalize, L1 mean + avg-MSE -> scalar
// Round-2 changes vs round-1:
//   * Gram via v_mfma_f32_32x32x16_bf16: 4 ds_read_b128 + 4 MFMA per lane/tile
//     instead of 128 ds_read_b128 + 256 VALU FMA per thread/tile
//   * bf16 LDS [32][256], XOR swizzle (elem ^= (row&7)<<3) -> bank-minimal
//   * double-buffered LDS, one barrier per tile
// ---------------------------------------------------------------------------

#define HW    262144          // 512*512
#define CHW   (3*HW)
#define NIMG  32
#define CPB   512             // pixel columns per block
#define GRIDX (HW / CPB)      // 512 blocks per tensor
#define NREP  8               // accumulator replicas

typedef __attribute__((ext_vector_type(4)))  __bf16 bf16x4;
typedef __attribute__((ext_vector_type(8)))  __bf16 bf16x8;
typedef __attribute__((ext_vector_type(16))) float  f32x16;

// RGB_FROM_HED and its inverse column 2 (DAB), computed exactly in double.
constexpr double M00=0.65, M01=0.70, M02=0.29;
constexpr double M10=0.07, M11=0.99, M12=0.11;
constexpr double M20=0.27, M21=0.57, M22=0.78;
constexpr double DETM = M00*(M11*M22-M12*M21) - M01*(M10*M22-M12*M20)
                      + M02*(M10*M21-M11*M20);
constexpr double H0d =  (M01*M12 - M02*M11) / DETM;   // hed_from_rgb[0][2]
constexpr double H1d = -(M00*M12 - M02*M10) / DETM;   // hed_from_rgb[1][2]
constexpr double H2d =  (M00*M11 - M01*M10) / DETM;   // hed_from_rgb[2][2]

#define H0 ((float)H0d)
#define H1 ((float)H1d)
#define H2 ((float)H2d)

// fod for one pixel. All transcendentals in base-2 HW ops.
//   d = max((h . ln(rgb))/ln(1e-6), 0)  ==>  LOG_ADJUST*d*log2e = min(h . log2(rgb), 0)
__device__ __forceinline__ float fod1(float r, float g, float b, float cal,
                                      float& racc) {
  float lr = __log2f(fmaxf(r, 1e-6f));
  float lg = __log2f(fmaxf(g, 1e-6f));
  float lb = __log2f(fmaxf(b, 1e-6f));
  float t2 = fminf(lr*H0 + lg*H1 + lb*H2, 0.0f);
  float e0 = exp2f(t2 * 0.27f);              // rgb_from_hed[2] weights
  float e1 = exp2f(t2 * 0.57f);
  float e2 = exp2f(t2 * 0.78f);
  float grey = fminf(e0*0.2125f + e1*0.7154f + e2*0.0721f, 1.0f);
  float x = fmaxf(-0.30102999566398120f * __log2f(grey + cal), 0.0f);
  float f = exp2f(1.8f * __log2f(x));        // x^1.8 ; x==0 -> exp2(-inf)=0
  racc += (f < 0.15f) ? 0.0f : f;            // THRESH_FOD
  return f;
}

// ws layout (floats):
//   gram: rep*2048 + tensor*1024 + e          [0, 16384)
//   avg : 16384 + rep*64 + tensor*32 + i      [16384, 16896)
__global__ __launch_bounds__(256, 4)
void od_gram_kernel(const float* __restrict__ tgt, const float* __restrict__ gen,
                    float* __restrict__ ws, float cal) {
  const float* img = blockIdx.y ? gen : tgt;
  const int rep = blockIdx.x & (NREP - 1);
  float* gram = ws + (rep << 11) + (blockIdx.y << 10);
  float* avgv = ws + 16384 + (rep << 6) + (blockIdx.y << 5);

  // F[buf][row=img 32][elem 256] bf16, XOR-swizzled: elem ^= (row&7)<<3.
  // Read (b128): 8 rows hit 8 distinct 16B slots = all 32 banks -> bank-minimal.
  __shared__ __bf16 F[2][NIMG * 256];

  const int t  = threadIdx.x;
  const int wv = t >> 6;        // wave id: phase A image-group, phase B k-quarter
  const int ln = t & 63;

  f32x16 acc;
  #pragma unroll
  for (int r = 0; r < 16; ++r) acc[r] = 0.0f;
  float avgp[8];
  #pragma unroll
  for (int r = 0; r < 8; ++r) avgp[r] = 0.0f;

  const int col0 = blockIdx.x * CPB;

  for (int tile = 0; tile < CPB / 256; ++tile) {
    const int k0 = col0 + (tile << 8);
    __bf16* Fb = F[tile & 1];

    // ---- Phase A: wave wv computes images [8wv, 8wv+8), lane ln pixels 4ln..4ln+3
    #pragma unroll 2
    for (int r = 0; r < 8; ++r) {
      const int b = (wv << 3) + r;
      const float* base = img + b * CHW + k0 + (ln << 2);
      float4 Rv = *(const float4*)(base);
      float4 Gv = *(const float4*)(base + HW);
      float4 Bv = *(const float4*)(base + 2 * HW);
      bf16x4 fo;
      fo[0] = (__bf16)fod1(Rv.x, Gv.x, Bv.x, cal, avgp[r]);
      fo[1] = (__bf16)fod1(Rv.y, Gv.y, Bv.y, cal, avgp[r]);
      fo[2] = (__bf16)fod1(Rv.z, Gv.z, Bv.z, cal, avgp[r]);
      fo[3] = (__bf16)fod1(Rv.w, Gv.w, Bv.w, cal, avgp[r]);
      const int idx = (b << 8) + (((ln << 2)) ^ ((b & 7) << 3));
      *(bf16x4*)&Fb[idx] = fo;
    }
    __syncthreads();

    // ---- Phase B: wave wv owns k-chunks [4wv, 4wv+4); G += mfma(a, a, G).
    // Lane reads F[ln&31][kc*16 + (ln>>5)*8 .. +7] (one b128); a-frag == b-frag.
    #pragma unroll
    for (int c = 0; c < 4; ++c) {
      const int kc = (wv << 2) + c;
      const int o  = (kc << 4) + ((ln >> 5) << 3);
      const int ridx = ((ln & 31) << 8) + (o ^ ((ln & 7) << 3));
      bf16x8 a = *(const bf16x8*)&F[tile & 1][ridx];
      acc = __builtin_amdgcn_mfma_f32_32x32x16_bf16(a, a, acc, 0, 0, 0);
    }
    // no second barrier: next tile writes the other buffer; the next
    // tile's barrier orders those writes after this tile's reads.
  }
  __syncthreads();   // all MFMA reads done before LDS reuse below

  // ---- fod_relu row sums: shuffle-reduce within wave, one atomic per row
  #pragma unroll
  for (int r = 0; r < 8; ++r) {
    float v = avgp[r];
    #pragma unroll
    for (int off = 32; off; off >>= 1) v += __shfl_down(v, off, 64);
    if (ln == 0) atomicAdd(&avgv[(wv << 3) + r], v);
  }

  // ---- Gram: cross-wave reduce in LDS (reuse F as f32 scratch), then atomics.
  // C/D layout (m74/m101): col=lane&31, row=(reg&3)+8*(reg>>2)+4*(lane>>5).
  {
    float* S = (float*)F;          // 256 threads * 16 f32 = 16 KB
    #pragma unroll
    for (int r = 0; r < 16; ++r) S[(t << 4) + r] = acc[r];
    __syncthreads();
    for (int e = t; e < 1024; e += 256) {
      const int i = e >> 5, j = e & 31;
      const int reg  = (i & 3) | ((i >> 3) << 2);
      const int lane = j | (((i >> 2) & 1) << 5);
      float sm = 0.0f;
      #pragma unroll
      for (int w2 = 0; w2 < 4; ++w2)
        sm += S[(((w2 << 6) + lane) << 4) + reg];
      atomicAdd(&gram[e], sm);
    }
  }
}

__global__ __launch_bounds__(256)
void finalize_kernel(const float* __restrict__ ws, float* __restrict__ out) {
  __shared__ float G[2048];
  __shared__ float A[64];
  __shared__ float nrm[64];
  __shared__ float wred[8];
  const int t = threadIdx.x;

  for (int e = t; e < 2048; e += 256) {
    float s = 0.0f;
    #pragma unroll
    for (int r = 0; r < NREP; ++r) s += ws[(r << 11) + e];
    G[e] = s;
  }
  if (t < 64) {
    float s = 0.0f;
    #pragma unroll
    for (int r = 0; r < NREP; ++r) s += ws[16384 + (r << 6) + t];
    A[t] = s;
  }
  __syncthreads();

  if (t < 64) {
    const int tensor = t >> 5, i = t & 31;
    nrm[t] = fmaxf(sqrtf(G[(tensor << 10) + i * 33]), 1e-8f);  // COS_EPS
  }
  __syncthreads();

  float s1 = 0.0f;
  for (int e = t; e < 1024; e += 256) {
    const int i = e >> 5, j = e & 31;
    const float ct = G[e]        / (nrm[i]      * nrm[j]);
    const float cg = G[1024 + e] / (nrm[32 + i] * nrm[32 + j]);
    s1 += fabsf(ct - cg);
  }
  float s2 = 0.0f;
  if (t < 32) {
    const float d = A[t] - A[32 + t];
    s2 = d * d;
  }
  #pragma unroll
  for (int off = 32; off; off >>= 1) {
    s1 += __shfl_down(s1, off, 64);
    s2 += __shfl_down(s2, off, 64);
  }
  if ((t & 63) == 0) { wred[t >> 6] = s1; wred[4 + (t >> 6)] = s2; }
  __syncthreads();
  if (t == 0) {
    const float a = wred[0] + wred[1] + wred[2] + wred[3];
    const float b = wred[4] + wred[5] + wred[6] + wred[7];
    const double hw2 = 262144.0 * 262144.0;
    out[0] = (float)((double)a / 1024.0 + ((double)b / 32.0) / hw2);
  }
}

extern "C" void kernel_launch(void* const* d_in, const int* in_sizes, int n_in,
                              void* d_out, int out_size, void* d_ws, size_t ws_size,
                              hipStream_t stream) {
  (void)in_sizes; (void)n_in; (void)out_size; (void)ws_size;
  const float* tgt = (const float*)d_in[1];
  const float* gen = (const float*)d_in[2];
  float* out = (float*)d_out;
  float* ws  = (float*)d_ws;

  hipMemsetAsync(d_ws, 0, 16896 * sizeof(float), stream);

  const float cal = (float)pow(10.0, -exp(1.0 / 1.8));  // ADJUST_CAL

  dim3 grid(GRIDX, 2);
  od_gram_kernel<<<grid, 256, 0, stream>>>(tgt, gen, ws, cal);
  finalize_kernel<<<1, 256, 0, stream>>>(ws, out);
}